// Round 11
// baseline (238.304 us; speedup 1.0000x reference)
//
#include <hip/hip_runtime.h>

#define BATCH 4096
#define NF 128
#define NW 128
#define NO 32
#define MT 64     // batch rows per block
#define LDH 136   // h stride in u16 (272B rows: 16B-aligned)

// d_ws (u16 elems): wh fp16 [l,f][v][k] | wo fp16 [f][o][k]  (k contiguous)
#define WH_ELEMS (2 * 128 * 128 * 128)
#define WO_ELEMS (128 * 128 * 32)

typedef _Float16 f16x8 __attribute__((ext_vector_type(8)));
typedef float f32x4 __attribute__((ext_vector_type(4)));

static __device__ __forceinline__ unsigned short f2h(float f) {
    return __builtin_bit_cast(unsigned short, (_Float16)f);  // RNE
}
static __device__ __forceinline__ unsigned long long pack4(float a, float b, float c, float d) {
    return (unsigned long long)f2h(a) | ((unsigned long long)f2h(b) << 16) |
           ((unsigned long long)f2h(c) << 32) | ((unsigned long long)f2h(d) << 48);
}

__global__ void zero_out_kernel(float* __restrict__ out, int n) {
    int i = blockIdx.x * blockDim.x + threadIdx.x;
    if (i < n) out[i] = 0.0f;
}

// Coalesced transpose + fp16 convert via LDS (stride 138 u16: conflict-free).
__global__ __launch_bounds__(256) void prep_weights2(
    const float* __restrict__ Wh, const float* __restrict__ Wo,
    unsigned short* __restrict__ ws) {
    __shared__ unsigned short t_sm[128 * 138];
    unsigned short* wh = ws;
    unsigned short* wo = ws + WH_ELEMS;
    const int b = blockIdx.x;
    const int tid = threadIdx.x;
    if (b < 256) {
        const float* src = Wh + (size_t)b * 16384;  // [k][v]
        for (int i = tid; i < 16384; i += 256) {
            int k = i >> 7, v = i & 127;
            t_sm[v * 138 + k] = f2h(src[i]);  // coalesced read
        }
        __syncthreads();
        unsigned short* dst = wh + (size_t)b * 16384;  // [v][k]
        for (int i = tid; i < 8192; i += 256) {
            int v = i >> 6, kp = i & 63;
            unsigned lo = t_sm[v * 138 + 2 * kp];
            unsigned hi = t_sm[v * 138 + 2 * kp + 1];
            *(unsigned*)&dst[v * 128 + 2 * kp] = lo | (hi << 16);  // coalesced write
        }
    } else {
        const int f = b - 256;
        const float* src = Wo + (size_t)f * 4096;  // [k][o]
        for (int i = tid; i < 4096; i += 256) {
            int k = i >> 5, o = i & 31;
            t_sm[o * 138 + k] = f2h(src[i]);
        }
        __syncthreads();
        unsigned short* dst = wo + (size_t)f * 4096;  // [o][k]
        for (int i = tid; i < 2048; i += 256) {
            int o = i >> 6, kp = i & 63;
            unsigned lo = t_sm[o * 138 + 2 * kp];
            unsigned hi = t_sm[o * 138 + 2 * kp + 1];
            *(unsigned*)&dst[o * 128 + 2 * kp] = lo | (hi << 16);
        }
    }
}

// Fused MLP chain, SWAPPED operands: C[v][m] = Wt . h^T. A = weight frag
// (reg, b128 from ws), B = h frag (ds_read_b128). Lane then holds 4
// consecutive v at fixed m -> ReLU writeback is ONE ds_write_b64 per tile
// (4x fewer LDS write instrs, no half-dword lane sharing), bias = float4.
// MT=64, 4 waves: acc[2][4]=32 + A[2][4]=32 regs -> fits (256,4), no spill.
__global__ __launch_bounds__(256, 4) void ngam_fused(
    const float* __restrict__ x, const float* __restrict__ W1,
    const float* __restrict__ b1, const float* __restrict__ bh,
    const float* __restrict__ bo, const unsigned short* __restrict__ ws,
    float* __restrict__ out) {
    __shared__ __align__(16) unsigned short h_sm[MT * LDH];
    const unsigned short* wh = ws;
    const unsigned short* wo = ws + WH_ELEMS;

    const int f    = blockIdx.x >> 6;        // feature (64 batch tiles each)
    const int m0   = (blockIdx.x & 63) * MT;
    const int tid  = threadIdx.x;
    const int wave = tid >> 6;               // 0..3: owns 32 v-cols of hidden
    const int lane = tid & 63;
    const int arow = lane & 15;              // A row (v or o) / B col (m)
    const int kgrp = lane >> 4;              // k-group; C row-quad

    // ---- layer 0: h = relu(x*W1+b1), fp32 exact -> fp16 LDS [m][w] ----
    {
        int m = tid >> 2, c = tid & 3;
        float xv = x[(size_t)(m0 + m) * NF + f];
        const float* w1r = &W1[f * NW];
        const float* b1r = &b1[f * NW];
#pragma unroll
        for (int j = 0; j < 8; ++j) {
            int wq = c * 32 + j * 4;
            float4 w1 = *(const float4*)&w1r[wq];
            float4 bb = *(const float4*)&b1r[wq];
            float v0 = fmaxf(xv * w1.x + bb.x, 0.0f);
            float v1 = fmaxf(xv * w1.y + bb.y, 0.0f);
            float v2 = fmaxf(xv * w1.z + bb.z, 0.0f);
            float v3 = fmaxf(xv * w1.w + bb.w, 0.0f);
            *(unsigned long long*)&h_sm[m * LDH + wq] = pack4(v0, v1, v2, v3);
        }
    }
    __syncthreads();

    // ---- two hidden layers (swapped-operand) ----
#pragma unroll
    for (int l = 0; l < 2; ++l) {
        const unsigned short* wp = wh + (size_t)(l * NF + f) * 16384;
        const float* bhl = bh + (size_t)(l * NF + f) * NW;

        f16x8 A[2][4];  // wave's 32 v-rows of Wt, whole layer (32 regs)
#pragma unroll
        for (int vt = 0; vt < 2; ++vt)
#pragma unroll
            for (int kt = 0; kt < 4; ++kt)
                A[vt][kt] = *(const f16x8*)&wp[(wave * 32 + vt * 16 + arow) * 128 + kt * 32 + kgrp * 8];

        f32x4 acc[2][4];  // [vt][mt] = 32 regs; init = bias (4 consecutive v)
#pragma unroll
        for (int vt = 0; vt < 2; ++vt) {
            float4 bb4 = *(const float4*)&bhl[wave * 32 + vt * 16 + kgrp * 4];
#pragma unroll
            for (int mt = 0; mt < 4; ++mt)
                acc[vt][mt] = (f32x4){bb4.x, bb4.y, bb4.z, bb4.w};
        }
#pragma unroll
        for (int mt = 0; mt < 4; ++mt) {
#pragma unroll
            for (int kt = 0; kt < 4; ++kt) {
                f16x8 bfr = *(const f16x8*)&h_sm[(mt * 16 + arow) * LDH + kt * 32 + kgrp * 8];
                acc[0][mt] = __builtin_amdgcn_mfma_f32_16x16x32_f16(A[0][kt], bfr, acc[0][mt], 0, 0, 0);
                acc[1][mt] = __builtin_amdgcn_mfma_f32_16x16x32_f16(A[1][kt], bfr, acc[1][mt], 0, 0, 0);
            }
        }
        __syncthreads();  // all waves done reading h
        // ReLU + writeback: lane holds v = wave*32+vt*16+kgrp*4+[0..3] at m=mt*16+arow
#pragma unroll
        for (int vt = 0; vt < 2; ++vt)
#pragma unroll
            for (int mt = 0; mt < 4; ++mt) {
                f32x4 v = acc[vt][mt];
                *(unsigned long long*)&h_sm[(mt * 16 + arow) * LDH + wave * 32 + vt * 16 + kgrp * 4] =
                    pack4(fmaxf(v[0], 0.f), fmaxf(v[1], 0.f), fmaxf(v[2], 0.f), fmaxf(v[3], 0.f));
            }
        __syncthreads();  // writeback visible
    }

    // ---- output layer (swapped): C[o][m]; wave: ot=wave&1, mh=wave>>1 ----
    {
        const int ot = wave & 1;
        const int mh = wave >> 1;
        const unsigned short* wop = wo + (size_t)f * 4096;
        const float* bof = bo + (size_t)f * NO;

        f16x8 Ao[4];
#pragma unroll
        for (int kt = 0; kt < 4; ++kt)
            Ao[kt] = *(const f16x8*)&wop[(ot * 16 + arow) * 128 + kt * 32 + kgrp * 8];

        float4 bb4 = *(const float4*)&bof[ot * 16 + kgrp * 4];
        f32x4 acc2[2];
        acc2[0] = (f32x4){bb4.x, bb4.y, bb4.z, bb4.w};
        acc2[1] = acc2[0];
#pragma unroll
        for (int mt2 = 0; mt2 < 2; ++mt2) {
#pragma unroll
            for (int kt = 0; kt < 4; ++kt) {
                f16x8 bfr = *(const f16x8*)&h_sm[(mh * 32 + mt2 * 16 + arow) * LDH + kt * 32 + kgrp * 8];
                acc2[mt2] = __builtin_amdgcn_mfma_f32_16x16x32_f16(Ao[kt], bfr, acc2[mt2], 0, 0, 0);
            }
        }
#pragma unroll
        for (int mt2 = 0; mt2 < 2; ++mt2)
#pragma unroll
            for (int r = 0; r < 4; ++r) {
                int row = m0 + mh * 32 + mt2 * 16 + arow;   // batch row (C col)
                int col = ot * 16 + kgrp * 4 + r;           // output col (C row)
                atomicAdd(&out[(size_t)row * NO + col], acc2[mt2][r]);
            }
    }
}

extern "C" void kernel_launch(void* const* d_in, const int* in_sizes, int n_in,
                              void* d_out, int out_size, void* d_ws, size_t ws_size,
                              hipStream_t stream) {
    const float* x  = (const float*)d_in[0];
    const float* W1 = (const float*)d_in[1];
    const float* b1 = (const float*)d_in[2];
    const float* Wh = (const float*)d_in[3];
    const float* bh = (const float*)d_in[4];
    const float* Wo = (const float*)d_in[5];
    const float* bo = (const float*)d_in[6];
    float* out = (float*)d_out;
    unsigned short* ws = (unsigned short*)d_ws;

    zero_out_kernel<<<(BATCH * NO + 255) / 256, 256, 0, stream>>>(out, BATCH * NO);
    prep_weights2<<<384, 256, 0, stream>>>(Wh, Wo, ws);
    ngam_fused<<<NF * (BATCH / MT), 256, 0, stream>>>(x, W1, b1, bh, bo, ws, out);
}

// Round 12
// 176.819 us; speedup vs baseline: 1.3477x; 1.3477x over previous
//
#include <hip/hip_runtime.h>

#define BATCH 4096
#define NF 128
#define NW 128
#define NO 32
#define MT 64     // batch rows per block
#define LDH 136   // h stride in u16 (272B rows: 16B-aligned)
#define FPB 2     // features per block (halves atomic traffic)

// d_ws (u16 elems): wh fp16 [l,f][v][k] | wo fp16 [f][o][k]  (k contiguous)
#define WH_ELEMS (2 * 128 * 128 * 128)
#define WO_ELEMS (128 * 128 * 32)

typedef _Float16 f16x8 __attribute__((ext_vector_type(8)));
typedef float f32x4 __attribute__((ext_vector_type(4)));

static __device__ __forceinline__ unsigned short f2h(float f) {
    return __builtin_bit_cast(unsigned short, (_Float16)f);  // RNE
}
static __device__ __forceinline__ unsigned long long pack4(float a, float b, float c, float d) {
    return (unsigned long long)f2h(a) | ((unsigned long long)f2h(b) << 16) |
           ((unsigned long long)f2h(c) << 32) | ((unsigned long long)f2h(d) << 48);
}

__global__ void zero_out_kernel(float* __restrict__ out, int n) {
    int i = blockIdx.x * blockDim.x + threadIdx.x;
    if (i < n) out[i] = 0.0f;
}

// Coalesced transpose + fp16 convert via LDS (stride 138 u16: conflict-free).
__global__ __launch_bounds__(256) void prep_weights2(
    const float* __restrict__ Wh, const float* __restrict__ Wo,
    unsigned short* __restrict__ ws) {
    __shared__ unsigned short t_sm[128 * 138];
    unsigned short* wh = ws;
    unsigned short* wo = ws + WH_ELEMS;
    const int b = blockIdx.x;
    const int tid = threadIdx.x;
    if (b < 256) {
        const float* src = Wh + (size_t)b * 16384;  // [k][v]
        for (int i = tid; i < 16384; i += 256) {
            int k = i >> 7, v = i & 127;
            t_sm[v * 138 + k] = f2h(src[i]);  // coalesced read
        }
        __syncthreads();
        unsigned short* dst = wh + (size_t)b * 16384;  // [v][k]
        for (int i = tid; i < 8192; i += 256) {
            int v = i >> 6, kp = i & 63;
            unsigned lo = t_sm[v * 138 + 2 * kp];
            unsigned hi = t_sm[v * 138 + 2 * kp + 1];
            *(unsigned*)&dst[v * 128 + 2 * kp] = lo | (hi << 16);  // coalesced write
        }
    } else {
        const int f = b - 256;
        const float* src = Wo + (size_t)f * 4096;  // [k][o]
        for (int i = tid; i < 4096; i += 256) {
            int k = i >> 5, o = i & 31;
            t_sm[o * 138 + k] = f2h(src[i]);
        }
        __syncthreads();
        unsigned short* dst = wo + (size_t)f * 4096;  // [o][k]
        for (int i = tid; i < 2048; i += 256) {
            int o = i >> 6, kp = i & 63;
            unsigned lo = t_sm[o * 138 + 2 * kp];
            unsigned hi = t_sm[o * 138 + 2 * kp + 1];
            *(unsigned*)&dst[o * 128 + 2 * kp] = lo | (hi << 16);
        }
    }
}

// Hybrid: hidden layers SWAPPED (C[v][m] = Wt.h^T -> b64 packed ReLU
// writeback, ~44 VGPR, r11-verified); output layer UNSWAPPED (C[m][o] ->
// wave-merged atomics: 16 lanes hit 16 consecutive dwords of one row,
// r9-verified; r11 lesson: lane-scattered rows cost 4x HBM write traffic).
__global__ __launch_bounds__(256, 6) void ngam_fused(
    const float* __restrict__ x, const float* __restrict__ W1,
    const float* __restrict__ b1, const float* __restrict__ bh,
    const float* __restrict__ bo, const unsigned short* __restrict__ ws,
    float* __restrict__ out) {
    __shared__ __align__(16) unsigned short h_sm[MT * LDH];
    const unsigned short* wh = ws;
    const unsigned short* wo = ws + WH_ELEMS;

    const int fpair = blockIdx.x >> 6;       // 0..63
    const int m0    = (blockIdx.x & 63) * MT;
    const int tid   = threadIdx.x;
    const int wave  = tid >> 6;              // 0..3
    const int lane  = tid & 63;
    const int arow  = lane & 15;             // A row (v/o) / B col (m) / C col
    const int kgrp  = lane >> 4;             // k-group; C row-quad
    const int r0    = wave * 16;             // wave's private rows (output stage)

    f32x4 oacc[2];  // output accumulator over features [ntl]
    oacc[0] = (f32x4){0.f, 0.f, 0.f, 0.f};
    oacc[1] = oacc[0];

    for (int fp = 0; fp < FPB; ++fp) {
        const int f = fpair + fp * (NF / FPB);

        // ---- layer 0: h = relu(x*W1+b1), fp32 exact -> fp16 LDS [m][w] ----
        {
            int m = tid >> 2, c = tid & 3;
            float xv = x[(size_t)(m0 + m) * NF + f];
            const float* w1r = &W1[f * NW];
            const float* b1r = &b1[f * NW];
#pragma unroll
            for (int j = 0; j < 8; ++j) {
                int wq = c * 32 + j * 4;
                float4 w1 = *(const float4*)&w1r[wq];
                float4 bb = *(const float4*)&b1r[wq];
                float v0 = fmaxf(xv * w1.x + bb.x, 0.0f);
                float v1 = fmaxf(xv * w1.y + bb.y, 0.0f);
                float v2 = fmaxf(xv * w1.z + bb.z, 0.0f);
                float v3 = fmaxf(xv * w1.w + bb.w, 0.0f);
                *(unsigned long long*)&h_sm[m * LDH + wq] = pack4(v0, v1, v2, v3);
            }
        }
        __syncthreads();

        // ---- two hidden layers (swapped-operand, r11-verified) ----
#pragma unroll
        for (int l = 0; l < 2; ++l) {
            const unsigned short* wp = wh + (size_t)(l * NF + f) * 16384;
            const float* bhl = bh + (size_t)(l * NF + f) * NW;

            f16x8 A[2][4];  // wave's 32 v-rows of Wt (32 regs)
#pragma unroll
            for (int vt = 0; vt < 2; ++vt)
#pragma unroll
                for (int kt = 0; kt < 4; ++kt)
                    A[vt][kt] = *(const f16x8*)&wp[(wave * 32 + vt * 16 + arow) * 128 + kt * 32 + kgrp * 8];

            f32x4 acc[2][4];  // [vt][mt]; init = bias (4 consecutive v)
#pragma unroll
            for (int vt = 0; vt < 2; ++vt) {
                float4 bb4 = *(const float4*)&bhl[wave * 32 + vt * 16 + kgrp * 4];
#pragma unroll
                for (int mt = 0; mt < 4; ++mt)
                    acc[vt][mt] = (f32x4){bb4.x, bb4.y, bb4.z, bb4.w};
            }
#pragma unroll
            for (int mt = 0; mt < 4; ++mt) {
#pragma unroll
                for (int kt = 0; kt < 4; ++kt) {
                    f16x8 bfr = *(const f16x8*)&h_sm[(mt * 16 + arow) * LDH + kt * 32 + kgrp * 8];
                    acc[0][mt] = __builtin_amdgcn_mfma_f32_16x16x32_f16(A[0][kt], bfr, acc[0][mt], 0, 0, 0);
                    acc[1][mt] = __builtin_amdgcn_mfma_f32_16x16x32_f16(A[1][kt], bfr, acc[1][mt], 0, 0, 0);
                }
            }
            __syncthreads();  // all waves done reading h
            // ReLU + b64 packed writeback: v = wave*32+vt*16+kgrp*4+[0..3], m = mt*16+arow
#pragma unroll
            for (int vt = 0; vt < 2; ++vt)
#pragma unroll
                for (int mt = 0; mt < 4; ++mt) {
                    f32x4 v = acc[vt][mt];
                    *(unsigned long long*)&h_sm[(mt * 16 + arow) * LDH + wave * 32 + vt * 16 + kgrp * 4] =
                        pack4(fmaxf(v[0], 0.f), fmaxf(v[1], 0.f), fmaxf(v[2], 0.f), fmaxf(v[3], 0.f));
                }
            __syncthreads();  // writeback visible
        }

        // ---- output layer (UNSWAPPED: wave's 16 rows, all 32 cols) ----
        {
            const unsigned short* wop = wo + (size_t)f * 4096;
            const float* bof = bo + (size_t)f * NO;
            f16x8 Bo[2][4];
#pragma unroll
            for (int ntl = 0; ntl < 2; ++ntl)
#pragma unroll
                for (int kt = 0; kt < 4; ++kt)
                    Bo[ntl][kt] = *(const f16x8*)&wop[(ntl * 16 + arow) * 128 + kt * 32 + kgrp * 8];
            f32x4 acc2[2];
#pragma unroll
            for (int ntl = 0; ntl < 2; ++ntl) {
                float bv = bof[ntl * 16 + arow];
                acc2[ntl] = (f32x4){bv, bv, bv, bv};
            }
#pragma unroll
            for (int kt = 0; kt < 4; ++kt) {
                f16x8 a = *(const f16x8*)&h_sm[(r0 + arow) * LDH + kt * 32 + kgrp * 8];
                acc2[0] = __builtin_amdgcn_mfma_f32_16x16x32_f16(a, Bo[0][kt], acc2[0], 0, 0, 0);
                acc2[1] = __builtin_amdgcn_mfma_f32_16x16x32_f16(a, Bo[1][kt], acc2[1], 0, 0, 0);
            }
            oacc[0] += acc2[0];
            oacc[1] += acc2[1];
        }
        __syncthreads();  // h_sm reads done before next feature's layer-0 fill
    }

    // ---- merged atomics (r9 pattern: consecutive cols across lanes) ----
#pragma unroll
    for (int ntl = 0; ntl < 2; ++ntl)
#pragma unroll
        for (int r = 0; r < 4; ++r) {
            int row = m0 + r0 + kgrp * 4 + r;
            int col = ntl * 16 + arow;
            atomicAdd(&out[(size_t)row * NO + col], oacc[ntl][r]);
        }
}

extern "C" void kernel_launch(void* const* d_in, const int* in_sizes, int n_in,
                              void* d_out, int out_size, void* d_ws, size_t ws_size,
                              hipStream_t stream) {
    const float* x  = (const float*)d_in[0];
    const float* W1 = (const float*)d_in[1];
    const float* b1 = (const float*)d_in[2];
    const float* Wh = (const float*)d_in[3];
    const float* bh = (const float*)d_in[4];
    const float* Wo = (const float*)d_in[5];
    const float* bo = (const float*)d_in[6];
    float* out = (float*)d_out;
    unsigned short* ws = (unsigned short*)d_ws;

    zero_out_kernel<<<(BATCH * NO + 255) / 256, 256, 0, stream>>>(out, BATCH * NO);
    prep_weights2<<<384, 256, 0, stream>>>(Wh, Wo, ws);
    ngam_fused<<<(NF / FPB) * (BATCH / MT), 256, 0, stream>>>(x, W1, b1, bh, bo, ws, out);
}

// Round 13
// 167.195 us; speedup vs baseline: 1.4253x; 1.0576x over previous
//
#include <hip/hip_runtime.h>

#define BATCH 4096
#define NF 128
#define NW 128
#define NO 32
#define MT 64     // batch rows per block
#define LDH 136   // h stride in u16 (272B rows: 16B-aligned)
#define FPB 2     // features per block (halves atomic traffic)

// d_ws (u16 elems): wh fp16 [l,f][v][k] | wo fp16 [f][o][k]  (k contiguous)
#define WH_ELEMS (2 * 128 * 128 * 128)
#define WO_ELEMS (128 * 128 * 32)

typedef _Float16 f16x8 __attribute__((ext_vector_type(8)));
typedef float f32x4 __attribute__((ext_vector_type(4)));

static __device__ __forceinline__ unsigned short f2h(float f) {
    return __builtin_bit_cast(unsigned short, (_Float16)f);  // RNE
}
static __device__ __forceinline__ unsigned long long pack4(float a, float b, float c, float d) {
    return (unsigned long long)f2h(a) | ((unsigned long long)f2h(b) << 16) |
           ((unsigned long long)f2h(c) << 32) | ((unsigned long long)f2h(d) << 48);
}

__global__ void zero_out_kernel(float* __restrict__ out, int n) {
    int i = blockIdx.x * blockDim.x + threadIdx.x;
    if (i < n) out[i] = 0.0f;
}

// Coalesced transpose + fp16 convert via LDS (stride 138 u16: conflict-free).
__global__ __launch_bounds__(256) void prep_weights2(
    const float* __restrict__ Wh, const float* __restrict__ Wo,
    unsigned short* __restrict__ ws) {
    __shared__ unsigned short t_sm[128 * 138];
    unsigned short* wh = ws;
    unsigned short* wo = ws + WH_ELEMS;
    const int b = blockIdx.x;
    const int tid = threadIdx.x;
    if (b < 256) {
        const float* src = Wh + (size_t)b * 16384;  // [k][v]
        for (int i = tid; i < 16384; i += 256) {
            int k = i >> 7, v = i & 127;
            t_sm[v * 138 + k] = f2h(src[i]);  // coalesced read
        }
        __syncthreads();
        unsigned short* dst = wh + (size_t)b * 16384;  // [v][k]
        for (int i = tid; i < 8192; i += 256) {
            int v = i >> 6, kp = i & 63;
            unsigned lo = t_sm[v * 138 + 2 * kp];
            unsigned hi = t_sm[v * 138 + 2 * kp + 1];
            *(unsigned*)&dst[v * 128 + 2 * kp] = lo | (hi << 16);  // coalesced write
        }
    } else {
        const int f = b - 256;
        const float* src = Wo + (size_t)f * 4096;  // [k][o]
        for (int i = tid; i < 4096; i += 256) {
            int k = i >> 5, o = i & 31;
            t_sm[o * 138 + k] = f2h(src[i]);
        }
        __syncthreads();
        unsigned short* dst = wo + (size_t)f * 4096;  // [o][k]
        for (int i = tid; i < 2048; i += 256) {
            int o = i >> 6, kp = i & 63;
            unsigned lo = t_sm[o * 138 + 2 * kp];
            unsigned hi = t_sm[o * 138 + 2 * kp + 1];
            *(unsigned*)&dst[o * 128 + 2 * kp] = lo | (hi << 16);
        }
    }
}

// r12 structure at the no-spill register cap: swapped hidden (b64 packed
// writeback), unswapped output (merged atomics), FPB=2. launch_bounds(256,4)
// -> cap 128 (r11-proven fit; r12's cap-85 spilled: L0's unrolled transient
// peak ~100 regs). L0 unroll split 2x4 to cut that transient.
__global__ __launch_bounds__(256, 4) void ngam_fused(
    const float* __restrict__ x, const float* __restrict__ W1,
    const float* __restrict__ b1, const float* __restrict__ bh,
    const float* __restrict__ bo, const unsigned short* __restrict__ ws,
    float* __restrict__ out) {
    __shared__ __align__(16) unsigned short h_sm[MT * LDH];
    const unsigned short* wh = ws;
    const unsigned short* wo = ws + WH_ELEMS;

    const int fpair = blockIdx.x >> 6;       // 0..63
    const int m0    = (blockIdx.x & 63) * MT;
    const int tid   = threadIdx.x;
    const int wave  = tid >> 6;              // 0..3
    const int lane  = tid & 63;
    const int arow  = lane & 15;             // A row (v/o) / B col (m) / C col
    const int kgrp  = lane >> 4;             // k-group; C row-quad
    const int r0    = wave * 16;             // wave's private rows (output stage)

    f32x4 oacc[2];  // output accumulator over features [ntl]
    oacc[0] = (f32x4){0.f, 0.f, 0.f, 0.f};
    oacc[1] = oacc[0];

    for (int fp = 0; fp < FPB; ++fp) {
        const int f = fpair + fp * (NF / FPB);

        // ---- layer 0: h = relu(x*W1+b1), fp32 exact -> fp16 LDS [m][w] ----
        {
            int m = tid >> 2, c = tid & 3;
            float xv = x[(size_t)(m0 + m) * NF + f];
            const float* w1r = &W1[f * NW];
            const float* b1r = &b1[f * NW];
            for (int jh = 0; jh < 2; ++jh) {  // two halves: lower transient reg peak
#pragma unroll
                for (int j = 0; j < 4; ++j) {
                    int wq = c * 32 + (jh * 4 + j) * 4;
                    float4 w1 = *(const float4*)&w1r[wq];
                    float4 bb = *(const float4*)&b1r[wq];
                    float v0 = fmaxf(xv * w1.x + bb.x, 0.0f);
                    float v1 = fmaxf(xv * w1.y + bb.y, 0.0f);
                    float v2 = fmaxf(xv * w1.z + bb.z, 0.0f);
                    float v3 = fmaxf(xv * w1.w + bb.w, 0.0f);
                    *(unsigned long long*)&h_sm[m * LDH + wq] = pack4(v0, v1, v2, v3);
                }
            }
        }
        __syncthreads();

        // ---- two hidden layers (swapped-operand: C[v][m] = Wt . h^T) ----
#pragma unroll
        for (int l = 0; l < 2; ++l) {
            const unsigned short* wp = wh + (size_t)(l * NF + f) * 16384;
            const float* bhl = bh + (size_t)(l * NF + f) * NW;

            f16x8 A[2][4];  // wave's 32 v-rows of Wt (32 regs)
#pragma unroll
            for (int vt = 0; vt < 2; ++vt)
#pragma unroll
                for (int kt = 0; kt < 4; ++kt)
                    A[vt][kt] = *(const f16x8*)&wp[(wave * 32 + vt * 16 + arow) * 128 + kt * 32 + kgrp * 8];

            f32x4 acc[2][4];  // [vt][mt]; init = bias (4 consecutive v)
#pragma unroll
            for (int vt = 0; vt < 2; ++vt) {
                float4 bb4 = *(const float4*)&bhl[wave * 32 + vt * 16 + kgrp * 4];
#pragma unroll
                for (int mt = 0; mt < 4; ++mt)
                    acc[vt][mt] = (f32x4){bb4.x, bb4.y, bb4.z, bb4.w};
            }
#pragma unroll
            for (int mt = 0; mt < 4; ++mt) {
#pragma unroll
                for (int kt = 0; kt < 4; ++kt) {
                    f16x8 bfr = *(const f16x8*)&h_sm[(mt * 16 + arow) * LDH + kt * 32 + kgrp * 8];
                    acc[0][mt] = __builtin_amdgcn_mfma_f32_16x16x32_f16(A[0][kt], bfr, acc[0][mt], 0, 0, 0);
                    acc[1][mt] = __builtin_amdgcn_mfma_f32_16x16x32_f16(A[1][kt], bfr, acc[1][mt], 0, 0, 0);
                }
            }
            __syncthreads();  // all waves done reading h
            // ReLU + b64 packed writeback: v = wave*32+vt*16+kgrp*4+[0..3], m = mt*16+arow
#pragma unroll
            for (int vt = 0; vt < 2; ++vt)
#pragma unroll
                for (int mt = 0; mt < 4; ++mt) {
                    f32x4 v = acc[vt][mt];
                    *(unsigned long long*)&h_sm[(mt * 16 + arow) * LDH + wave * 32 + vt * 16 + kgrp * 4] =
                        pack4(fmaxf(v[0], 0.f), fmaxf(v[1], 0.f), fmaxf(v[2], 0.f), fmaxf(v[3], 0.f));
                }
            __syncthreads();  // writeback visible
        }

        // ---- output layer (UNSWAPPED: wave's 16 rows, all 32 cols) ----
        {
            const unsigned short* wop = wo + (size_t)f * 4096;
            const float* bof = bo + (size_t)f * NO;
            f16x8 Bo[2][4];
#pragma unroll
            for (int ntl = 0; ntl < 2; ++ntl)
#pragma unroll
                for (int kt = 0; kt < 4; ++kt)
                    Bo[ntl][kt] = *(const f16x8*)&wop[(ntl * 16 + arow) * 128 + kt * 32 + kgrp * 8];
            f32x4 acc2[2];
#pragma unroll
            for (int ntl = 0; ntl < 2; ++ntl) {
                float bv = bof[ntl * 16 + arow];
                acc2[ntl] = (f32x4){bv, bv, bv, bv};
            }
#pragma unroll
            for (int kt = 0; kt < 4; ++kt) {
                f16x8 a = *(const f16x8*)&h_sm[(r0 + arow) * LDH + kt * 32 + kgrp * 8];
                acc2[0] = __builtin_amdgcn_mfma_f32_16x16x32_f16(a, Bo[0][kt], acc2[0], 0, 0, 0);
                acc2[1] = __builtin_amdgcn_mfma_f32_16x16x32_f16(a, Bo[1][kt], acc2[1], 0, 0, 0);
            }
            oacc[0] += acc2[0];
            oacc[1] += acc2[1];
        }
        __syncthreads();  // h_sm reads done before next feature's layer-0 fill
    }

    // ---- merged atomics (16 lanes -> 16 consecutive dwords of one row) ----
#pragma unroll
    for (int ntl = 0; ntl < 2; ++ntl)
#pragma unroll
        for (int r = 0; r < 4; ++r) {
            int row = m0 + r0 + kgrp * 4 + r;
            int col = ntl * 16 + arow;
            atomicAdd(&out[(size_t)row * NO + col], oacc[ntl][r]);
        }
}

extern "C" void kernel_launch(void* const* d_in, const int* in_sizes, int n_in,
                              void* d_out, int out_size, void* d_ws, size_t ws_size,
                              hipStream_t stream) {
    const float* x  = (const float*)d_in[0];
    const float* W1 = (const float*)d_in[1];
    const float* b1 = (const float*)d_in[2];
    const float* Wh = (const float*)d_in[3];
    const float* bh = (const float*)d_in[4];
    const float* Wo = (const float*)d_in[5];
    const float* bo = (const float*)d_in[6];
    float* out = (float*)d_out;
    unsigned short* ws = (unsigned short*)d_ws;

    zero_out_kernel<<<(BATCH * NO + 255) / 256, 256, 0, stream>>>(out, BATCH * NO);
    prep_weights2<<<384, 256, 0, stream>>>(Wh, Wo, ws);
    ngam_fused<<<(NF / FPB) * (BATCH / MT), 256, 0, stream>>>(x, W1, b1, bh, bo, ws, out);
}

// Round 14
// 119.270 us; speedup vs baseline: 1.9980x; 1.4018x over previous
//
#include <hip/hip_runtime.h>

#define BATCH 4096
#define NF 128
#define NW 128
#define NO 32
#define MT 128    // batch rows per block
#define LDH 136   // h stride in u16 (272B rows: 16B-aligned, 2-way banks = free)
#define FPB 2     // features per block (halves atomic traffic)

// d_ws (u16 elems): wh fp16 [l,f][v][k] | wo fp16 [f][o][k]  (k contiguous)
#define WH_ELEMS (2 * 128 * 128 * 128)
#define WO_ELEMS (128 * 128 * 32)

typedef _Float16 f16x8 __attribute__((ext_vector_type(8)));
typedef float f32x4 __attribute__((ext_vector_type(4)));

static __device__ __forceinline__ unsigned short f2h(float f) {
    return __builtin_bit_cast(unsigned short, (_Float16)f);  // RNE
}
static __device__ __forceinline__ unsigned long long pack4(float a, float b, float c, float d) {
    return (unsigned long long)f2h(a) | ((unsigned long long)f2h(b) << 16) |
           ((unsigned long long)f2h(c) << 32) | ((unsigned long long)f2h(d) << 48);
}

__global__ void zero_out_kernel(float* __restrict__ out, int n) {
    int i = blockIdx.x * blockDim.x + threadIdx.x;
    if (i < n) out[i] = 0.0f;
}

// Coalesced transpose + fp16 convert via LDS (stride 138 u16: conflict-free).
__global__ __launch_bounds__(256) void prep_weights2(
    const float* __restrict__ Wh, const float* __restrict__ Wo,
    unsigned short* __restrict__ ws) {
    __shared__ unsigned short t_sm[128 * 138];
    unsigned short* wh = ws;
    unsigned short* wo = ws + WH_ELEMS;
    const int b = blockIdx.x;
    const int tid = threadIdx.x;
    if (b < 256) {
        const float* src = Wh + (size_t)b * 16384;  // [k][v]
        for (int i = tid; i < 16384; i += 256) {
            int k = i >> 7, v = i & 127;
            t_sm[v * 138 + k] = f2h(src[i]);  // coalesced read
        }
        __syncthreads();
        unsigned short* dst = wh + (size_t)b * 16384;  // [v][k]
        for (int i = tid; i < 8192; i += 256) {
            int v = i >> 6, kp = i & 63;
            unsigned lo = t_sm[v * 138 + 2 * kp];
            unsigned hi = t_sm[v * 138 + 2 * kp + 1];
            *(unsigned*)&dst[v * 128 + 2 * kp] = lo | (hi << 16);  // coalesced write
        }
    } else {
        const int f = b - 256;
        const float* src = Wo + (size_t)f * 4096;  // [k][o]
        for (int i = tid; i < 4096; i += 256) {
            int k = i >> 5, o = i & 31;
            t_sm[o * 138 + k] = f2h(src[i]);
        }
        __syncthreads();
        unsigned short* dst = wo + (size_t)f * 4096;  // [o][k]
        for (int i = tid; i < 2048; i += 256) {
            int o = i >> 6, kp = i & 63;
            unsigned lo = t_sm[o * 138 + 2 * kp];
            unsigned hi = t_sm[o * 138 + 2 * kp + 1];
            *(unsigned*)&dst[o * 128 + 2 * kp] = lo | (hi << 16);
        }
    }
}

// 64-MFMA phases at cap-128 (r13 lesson: phase size is the lever; 32-MFMA
// phases = 160-172us, 64-MFMA = 129-137us regardless of occupancy).
// Swapped hidden: wave owns 32 v-rows x ALL 128 m -> acc[2][8]=64 + A[2][4]=32
// regs (the swap makes the weight operand the small one). Unswapped output
// (merged atomics, r11 lesson). FPB=2. b64 packed ReLU writeback.
__global__ __launch_bounds__(256, 4) void ngam_fused(
    const float* __restrict__ x, const float* __restrict__ W1,
    const float* __restrict__ b1, const float* __restrict__ bh,
    const float* __restrict__ bo, const unsigned short* __restrict__ ws,
    float* __restrict__ out) {
    __shared__ __align__(16) unsigned short h_sm[MT * LDH];
    const unsigned short* wh = ws;
    const unsigned short* wo = ws + WH_ELEMS;

    const int fpair = blockIdx.x >> 5;       // 0..63
    const int m0    = (blockIdx.x & 31) * MT;
    const int tid   = threadIdx.x;
    const int wave  = tid >> 6;              // 0..3: owns 32 v-rows (hidden)
    const int lane  = tid & 63;
    const int arow  = lane & 15;             // A row (v/o) / B col (m) / C col
    const int kgrp  = lane >> 4;             // k-group; C row-quad
    const int r0    = wave * 32;             // wave's private rows (output stage)

    f32x4 oacc[2][2];  // output accumulator over features [mt2][ntl]
#pragma unroll
    for (int a = 0; a < 2; ++a)
#pragma unroll
        for (int b = 0; b < 2; ++b) oacc[a][b] = (f32x4){0.f, 0.f, 0.f, 0.f};

    for (int fp = 0; fp < FPB; ++fp) {
        const int f = fpair + fp * (NF / FPB);

        // ---- layer 0: h = relu(x*W1+b1), fp32 exact -> fp16 LDS [m][w] ----
        {
            int m = tid >> 1, c = tid & 1;
            float xv = x[(size_t)(m0 + m) * NF + f];
            const float* w1r = &W1[f * NW];
            const float* b1r = &b1[f * NW];
            for (int jh = 0; jh < 2; ++jh) {  // split unroll: lower reg transient
#pragma unroll
                for (int j = 0; j < 8; ++j) {
                    int wq = c * 64 + (jh * 8 + j) * 4;
                    float4 w1 = *(const float4*)&w1r[wq];
                    float4 bb = *(const float4*)&b1r[wq];
                    float v0 = fmaxf(xv * w1.x + bb.x, 0.0f);
                    float v1 = fmaxf(xv * w1.y + bb.y, 0.0f);
                    float v2 = fmaxf(xv * w1.z + bb.z, 0.0f);
                    float v3 = fmaxf(xv * w1.w + bb.w, 0.0f);
                    *(unsigned long long*)&h_sm[m * LDH + wq] = pack4(v0, v1, v2, v3);
                }
            }
        }
        __syncthreads();

        // ---- two hidden layers (swapped: C[v][m] = Wt . h^T) ----
#pragma unroll
        for (int l = 0; l < 2; ++l) {
            const unsigned short* wp = wh + (size_t)(l * NF + f) * 16384;
            const float* bhl = bh + (size_t)(l * NF + f) * NW;

            f16x8 A[2][4];  // wave's 32 v-rows of Wt (32 regs)
#pragma unroll
            for (int vt = 0; vt < 2; ++vt)
#pragma unroll
                for (int kt = 0; kt < 4; ++kt)
                    A[vt][kt] = *(const f16x8*)&wp[(wave * 32 + vt * 16 + arow) * 128 + kt * 32 + kgrp * 8];

            f32x4 acc[2][8];  // [vt][mt] = 64 regs; init = bias (4 consecutive v)
#pragma unroll
            for (int vt = 0; vt < 2; ++vt) {
                float4 bb4 = *(const float4*)&bhl[wave * 32 + vt * 16 + kgrp * 4];
#pragma unroll
                for (int mt = 0; mt < 8; ++mt)
                    acc[vt][mt] = (f32x4){bb4.x, bb4.y, bb4.z, bb4.w};
            }
#pragma unroll
            for (int mt = 0; mt < 8; ++mt) {
#pragma unroll
                for (int kt = 0; kt < 4; ++kt) {
                    f16x8 bfr = *(const f16x8*)&h_sm[(mt * 16 + arow) * LDH + kt * 32 + kgrp * 8];
                    acc[0][mt] = __builtin_amdgcn_mfma_f32_16x16x32_f16(A[0][kt], bfr, acc[0][mt], 0, 0, 0);
                    acc[1][mt] = __builtin_amdgcn_mfma_f32_16x16x32_f16(A[1][kt], bfr, acc[1][mt], 0, 0, 0);
                }
            }
            __syncthreads();  // all waves done reading h
            // ReLU + b64 packed writeback: v = wave*32+vt*16+kgrp*4+[0..3], m = mt*16+arow
#pragma unroll
            for (int vt = 0; vt < 2; ++vt)
#pragma unroll
                for (int mt = 0; mt < 8; ++mt) {
                    f32x4 v = acc[vt][mt];
                    *(unsigned long long*)&h_sm[(mt * 16 + arow) * LDH + wave * 32 + vt * 16 + kgrp * 4] =
                        pack4(fmaxf(v[0], 0.f), fmaxf(v[1], 0.f), fmaxf(v[2], 0.f), fmaxf(v[3], 0.f));
                }
            __syncthreads();  // writeback visible
        }

        // ---- output layer (UNSWAPPED: wave's 32 rows, all 32 cols) ----
        {
            const unsigned short* wop = wo + (size_t)f * 4096;
            const float* bof = bo + (size_t)f * NO;
            f16x8 Bo[2][4];
#pragma unroll
            for (int ntl = 0; ntl < 2; ++ntl)
#pragma unroll
                for (int kt = 0; kt < 4; ++kt)
                    Bo[ntl][kt] = *(const f16x8*)&wop[(ntl * 16 + arow) * 128 + kt * 32 + kgrp * 8];
            f32x4 acc2[2][2];
#pragma unroll
            for (int ntl = 0; ntl < 2; ++ntl) {
                float bv = bof[ntl * 16 + arow];
                acc2[0][ntl] = (f32x4){bv, bv, bv, bv};
                acc2[1][ntl] = acc2[0][ntl];
            }
#pragma unroll
            for (int mt2 = 0; mt2 < 2; ++mt2) {
#pragma unroll
                for (int kt = 0; kt < 4; ++kt) {
                    f16x8 a = *(const f16x8*)&h_sm[(r0 + mt2 * 16 + arow) * LDH + kt * 32 + kgrp * 8];
                    acc2[mt2][0] = __builtin_amdgcn_mfma_f32_16x16x32_f16(a, Bo[0][kt], acc2[mt2][0], 0, 0, 0);
                    acc2[mt2][1] = __builtin_amdgcn_mfma_f32_16x16x32_f16(a, Bo[1][kt], acc2[mt2][1], 0, 0, 0);
                }
            }
#pragma unroll
            for (int mt2 = 0; mt2 < 2; ++mt2)
#pragma unroll
                for (int ntl = 0; ntl < 2; ++ntl) oacc[mt2][ntl] += acc2[mt2][ntl];
        }
        __syncthreads();  // h_sm reads done before next feature's layer-0 fill
    }

    // ---- merged atomics (16 lanes -> 16 consecutive dwords of one row) ----
#pragma unroll
    for (int mt2 = 0; mt2 < 2; ++mt2)
#pragma unroll
        for (int ntl = 0; ntl < 2; ++ntl)
#pragma unroll
            for (int r = 0; r < 4; ++r) {
                int row = m0 + r0 + mt2 * 16 + kgrp * 4 + r;
                int col = ntl * 16 + arow;
                atomicAdd(&out[(size_t)row * NO + col], oacc[mt2][ntl][r]);
            }
}

extern "C" void kernel_launch(void* const* d_in, const int* in_sizes, int n_in,
                              void* d_out, int out_size, void* d_ws, size_t ws_size,
                              hipStream_t stream) {
    const float* x  = (const float*)d_in[0];
    const float* W1 = (const float*)d_in[1];
    const float* b1 = (const float*)d_in[2];
    const float* Wh = (const float*)d_in[3];
    const float* bh = (const float*)d_in[4];
    const float* Wo = (const float*)d_in[5];
    const float* bo = (const float*)d_in[6];
    float* out = (float*)d_out;
    unsigned short* ws = (unsigned short*)d_ws;

    zero_out_kernel<<<(BATCH * NO + 255) / 256, 256, 0, stream>>>(out, BATCH * NO);
    prep_weights2<<<384, 256, 0, stream>>>(Wh, Wo, ws);
    ngam_fused<<<(NF / FPB) * (BATCH / MT), 256, 0, stream>>>(x, W1, b1, bh, bo, ws, out);
}

// Round 15
// 109.247 us; speedup vs baseline: 2.1813x; 1.0917x over previous
//
#include <hip/hip_runtime.h>

#define BATCH 4096
#define NF 128
#define NW 128
#define NO 32
#define MT 128    // batch rows per block
#define LDH 136   // h stride in u16 (272B rows: 16B-aligned, 2-way banks = free)

// d_ws (u16 elems): wh fp16 [l,f][v][k] | wo fp16 [f][o][k]  (k contiguous)
#define WH_ELEMS (2 * 128 * 128 * 128)
#define WO_ELEMS (128 * 128 * 32)

typedef _Float16 f16x8 __attribute__((ext_vector_type(8)));
typedef float f32x4 __attribute__((ext_vector_type(4)));

static __device__ __forceinline__ unsigned short f2h(float f) {
    return __builtin_bit_cast(unsigned short, (_Float16)f);  // RNE
}
static __device__ __forceinline__ unsigned long long pack4(float a, float b, float c, float d) {
    return (unsigned long long)f2h(a) | ((unsigned long long)f2h(b) << 16) |
           ((unsigned long long)f2h(c) << 32) | ((unsigned long long)f2h(d) << 48);
}

__global__ void zero_out_kernel(float* __restrict__ out, int n) {
    int i = blockIdx.x * blockDim.x + threadIdx.x;
    if (i < n) out[i] = 0.0f;
}

// Coalesced transpose + fp16 convert via LDS (stride 138 u16: conflict-free).
__global__ __launch_bounds__(256) void prep_weights2(
    const float* __restrict__ Wh, const float* __restrict__ Wo,
    unsigned short* __restrict__ ws) {
    __shared__ unsigned short t_sm[128 * 138];
    unsigned short* wh = ws;
    unsigned short* wo = ws + WH_ELEMS;
    const int b = blockIdx.x;
    const int tid = threadIdx.x;
    if (b < 256) {
        const float* src = Wh + (size_t)b * 16384;  // [k][v]
        for (int i = tid; i < 16384; i += 256) {
            int k = i >> 7, v = i & 127;
            t_sm[v * 138 + k] = f2h(src[i]);  // coalesced read
        }
        __syncthreads();
        unsigned short* dst = wh + (size_t)b * 16384;  // [v][k]
        for (int i = tid; i < 8192; i += 256) {
            int v = i >> 6, kp = i & 63;
            unsigned lo = t_sm[v * 138 + 2 * kp];
            unsigned hi = t_sm[v * 138 + 2 * kp + 1];
            *(unsigned*)&dst[v * 128 + 2 * kp] = lo | (hi << 16);  // coalesced write
        }
    } else {
        const int f = b - 256;
        const float* src = Wo + (size_t)f * 4096;  // [k][o]
        for (int i = tid; i < 4096; i += 256) {
            int k = i >> 5, o = i & 31;
            t_sm[o * 138 + k] = f2h(src[i]);
        }
        __syncthreads();
        unsigned short* dst = wo + (size_t)f * 4096;  // [o][k]
        for (int i = tid; i < 2048; i += 256) {
            int o = i >> 6, kp = i & 63;
            unsigned lo = t_sm[o * 138 + 2 * kp];
            unsigned hi = t_sm[o * 138 + 2 * kp + 1];
            *(unsigned*)&dst[o * 128 + 2 * kp] = lo | (hi << 16);
        }
    }
}

// 64-MFMA phases WITHOUT spill: FPB=1 (no oacc) + A loaded in k-halves
// (A[2][2]=16 regs, same 16 total b128 loads). Peak live = acc(64)+A(16)
// +temps ~= 95 < 128-cap of (256,4). r14 proved 64-MFMA phases are the
// lever (112us even WITH ~130MB scratch traffic); this removes the spill.
__global__ __launch_bounds__(256, 4) void ngam_fused(
    const float* __restrict__ x, const float* __restrict__ W1,
    const float* __restrict__ b1, const float* __restrict__ bh,
    const float* __restrict__ bo, const unsigned short* __restrict__ ws,
    float* __restrict__ out) {
    __shared__ __align__(16) unsigned short h_sm[MT * LDH];
    const unsigned short* wh = ws;
    const unsigned short* wo = ws + WH_ELEMS;

    const int f    = blockIdx.x >> 5;        // feature (32 batch tiles each)
    const int m0   = (blockIdx.x & 31) * MT;
    const int tid  = threadIdx.x;
    const int wave = tid >> 6;               // 0..3: owns 32 v-rows (hidden)
    const int lane = tid & 63;
    const int arow = lane & 15;              // A row (v/o) / B col (m) / C col
    const int kgrp = lane >> 4;              // k-group; C row-quad
    const int r0   = wave * 32;              // wave's private rows (output stage)

    // ---- layer 0: h = relu(x*W1+b1), fp32 exact -> fp16 LDS [m][w] ----
    {
        int m = tid >> 1, c = tid & 1;
        float xv = x[(size_t)(m0 + m) * NF + f];
        const float* w1r = &W1[f * NW];
        const float* b1r = &b1[f * NW];
        for (int jh = 0; jh < 2; ++jh) {  // split unroll: lower reg transient
#pragma unroll
            for (int j = 0; j < 8; ++j) {
                int wq = c * 64 + (jh * 8 + j) * 4;
                float4 w1 = *(const float4*)&w1r[wq];
                float4 bb = *(const float4*)&b1r[wq];
                float v0 = fmaxf(xv * w1.x + bb.x, 0.0f);
                float v1 = fmaxf(xv * w1.y + bb.y, 0.0f);
                float v2 = fmaxf(xv * w1.z + bb.z, 0.0f);
                float v3 = fmaxf(xv * w1.w + bb.w, 0.0f);
                *(unsigned long long*)&h_sm[m * LDH + wq] = pack4(v0, v1, v2, v3);
            }
        }
    }
    __syncthreads();

    // ---- two hidden layers (swapped: C[v][m] = Wt . h^T) ----
#pragma unroll
    for (int l = 0; l < 2; ++l) {
        const unsigned short* wp = wh + (size_t)(l * NF + f) * 16384;
        const float* bhl = bh + (size_t)(l * NF + f) * NW;

        f32x4 acc[2][8];  // [vt][mt] = 64 regs; init = bias (4 consecutive v)
#pragma unroll
        for (int vt = 0; vt < 2; ++vt) {
            float4 bb4 = *(const float4*)&bhl[wave * 32 + vt * 16 + kgrp * 4];
#pragma unroll
            for (int mt = 0; mt < 8; ++mt)
                acc[vt][mt] = (f32x4){bb4.x, bb4.y, bb4.z, bb4.w};
        }
#pragma unroll
        for (int kh = 0; kh < 2; ++kh) {  // A k-half residency: 16 regs
            f16x8 A[2][2];  // [vt][kt2]
#pragma unroll
            for (int vt = 0; vt < 2; ++vt)
#pragma unroll
                for (int kt2 = 0; kt2 < 2; ++kt2)
                    A[vt][kt2] = *(const f16x8*)&wp[(wave * 32 + vt * 16 + arow) * 128 +
                                                    (kh * 2 + kt2) * 32 + kgrp * 8];
#pragma unroll
            for (int mt = 0; mt < 8; ++mt) {
#pragma unroll
                for (int kt2 = 0; kt2 < 2; ++kt2) {
                    f16x8 bfr = *(const f16x8*)&h_sm[(mt * 16 + arow) * LDH +
                                                     (kh * 2 + kt2) * 32 + kgrp * 8];
                    acc[0][mt] = __builtin_amdgcn_mfma_f32_16x16x32_f16(A[0][kt2], bfr, acc[0][mt], 0, 0, 0);
                    acc[1][mt] = __builtin_amdgcn_mfma_f32_16x16x32_f16(A[1][kt2], bfr, acc[1][mt], 0, 0, 0);
                }
            }
        }
        __syncthreads();  // all waves done reading h
        // ReLU + b64 packed writeback: v = wave*32+vt*16+kgrp*4+[0..3], m = mt*16+arow
#pragma unroll
        for (int vt = 0; vt < 2; ++vt)
#pragma unroll
            for (int mt = 0; mt < 8; ++mt) {
                f32x4 v = acc[vt][mt];
                *(unsigned long long*)&h_sm[(mt * 16 + arow) * LDH + wave * 32 + vt * 16 + kgrp * 4] =
                    pack4(fmaxf(v[0], 0.f), fmaxf(v[1], 0.f), fmaxf(v[2], 0.f), fmaxf(v[3], 0.f));
            }
        __syncthreads();  // writeback visible
    }

    // ---- output layer (UNSWAPPED: wave's 32 rows, all 32 cols) + atomics ----
    {
        const unsigned short* wop = wo + (size_t)f * 4096;
        const float* bof = bo + (size_t)f * NO;
        f16x8 Bo[2][4];
#pragma unroll
        for (int ntl = 0; ntl < 2; ++ntl)
#pragma unroll
            for (int kt = 0; kt < 4; ++kt)
                Bo[ntl][kt] = *(const f16x8*)&wop[(ntl * 16 + arow) * 128 + kt * 32 + kgrp * 8];
        f32x4 acc2[2][2];
#pragma unroll
        for (int ntl = 0; ntl < 2; ++ntl) {
            float bv = bof[ntl * 16 + arow];
            acc2[0][ntl] = (f32x4){bv, bv, bv, bv};
            acc2[1][ntl] = acc2[0][ntl];
        }
#pragma unroll
        for (int mt2 = 0; mt2 < 2; ++mt2) {
#pragma unroll
            for (int kt = 0; kt < 4; ++kt) {
                f16x8 a = *(const f16x8*)&h_sm[(r0 + mt2 * 16 + arow) * LDH + kt * 32 + kgrp * 8];
                acc2[mt2][0] = __builtin_amdgcn_mfma_f32_16x16x32_f16(a, Bo[0][kt], acc2[mt2][0], 0, 0, 0);
                acc2[mt2][1] = __builtin_amdgcn_mfma_f32_16x16x32_f16(a, Bo[1][kt], acc2[mt2][1], 0, 0, 0);
            }
        }
        // merged atomics (16 lanes -> 16 consecutive dwords of one row)
#pragma unroll
        for (int mt2 = 0; mt2 < 2; ++mt2)
#pragma unroll
            for (int ntl = 0; ntl < 2; ++ntl)
#pragma unroll
                for (int r = 0; r < 4; ++r) {
                    int row = m0 + r0 + mt2 * 16 + kgrp * 4 + r;
                    int col = ntl * 16 + arow;
                    atomicAdd(&out[(size_t)row * NO + col], acc2[mt2][ntl][r]);
                }
    }
}

extern "C" void kernel_launch(void* const* d_in, const int* in_sizes, int n_in,
                              void* d_out, int out_size, void* d_ws, size_t ws_size,
                              hipStream_t stream) {
    const float* x  = (const float*)d_in[0];
    const float* W1 = (const float*)d_in[1];
    const float* b1 = (const float*)d_in[2];
    const float* Wh = (const float*)d_in[3];
    const float* bh = (const float*)d_in[4];
    const float* Wo = (const float*)d_in[5];
    const float* bo = (const float*)d_in[6];
    float* out = (float*)d_out;
    unsigned short* ws = (unsigned short*)d_ws;

    zero_out_kernel<<<(BATCH * NO + 255) / 256, 256, 0, stream>>>(out, BATCH * NO);
    prep_weights2<<<384, 256, 0, stream>>>(Wh, Wo, ws);
    ngam_fused<<<NF * (BATCH / MT), 256, 0, stream>>>(x, W1, b1, bh, bo, ws, out);
}